// Round 1
// 800.042 us; speedup vs baseline: 1.2102x; 1.2102x over previous
//
#include <hip/hip_runtime.h>
#include <stdint.h>
#include <stddef.h>

typedef __bf16 bf16;
typedef __attribute__((ext_vector_type(8))) __bf16 bf16x8;
typedef __attribute__((ext_vector_type(4))) __bf16 bf16x4;
typedef __attribute__((ext_vector_type(4))) float floatx4;

#define DEV static __device__ __forceinline__

// async global->LDS, 16B per lane. LDS dest is wave-uniform base + lane*16.
DEV void async_load16(const void* g, void* l) {
  __builtin_amdgcn_global_load_lds(
      (__attribute__((address_space(1))) void*)(g),
      (__attribute__((address_space(3))) void*)(l),
      16, 0, 0);
}

DEV float bf16lo_to_f(uint32_t pv) {
  uint32_t b = pv << 16; float f; __builtin_memcpy(&f, &b, 4); return f;
}
DEV float bf16hi_to_f(uint32_t pv) {
  uint32_t b = pv & 0xffff0000u; float f; __builtin_memcpy(&f, &b, 4); return f;
}

// W_in row permutation: new row c holds logical channel p = (c>>5)*16 + (c&15),
// s-half if (c>>4)&1 == 0 else b-half (orig row p + 2048).
DEV int win_orig_row(int c) {
  int jt16 = c >> 4;
  int is_b = jt16 & 1;
  int p    = (jt16 >> 1) * 16 + (c & 15);
  return p + is_b * 2048;
}

// ---------------------------------------------------------------------------
// fp32 -> bf16 convert (generic, for W_out)
// ---------------------------------------------------------------------------
__global__ __launch_bounds__(256)
void f2bf_kernel(const float* __restrict__ in, bf16* __restrict__ out, int n4)
{
  int i = blockIdx.x * 256 + threadIdx.x;
  if (i < n4) {
    float4 v = ((const float4*)in)[i];
    bf16x4 o = { (bf16)v.x, (bf16)v.y, (bf16)v.z, (bf16)v.w };
    ((bf16x4*)out)[i] = o;
  }
}

// fp32 -> bf16 convert of W_in with row permutation (one block per new row)
__global__ __launch_bounds__(256)
void f2bf_win_perm(const float* __restrict__ in, bf16* __restrict__ out)
{
  int c = blockIdx.x;                    // new row 0..4095
  int orig = win_orig_row(c);
  float4 v = ((const float4*)(in + (size_t)orig * 1024))[threadIdx.x];
  bf16x4 o = { (bf16)v.x, (bf16)v.y, (bf16)v.z, (bf16)v.w };
  ((bf16x4*)(out + (size_t)c * 1024))[threadIdx.x] = o;
}

__global__ __launch_bounds__(256)
void bias_perm_kernel(const float* __restrict__ b_in, float* __restrict__ biasP)
{
  int c = blockIdx.x * 256 + threadIdx.x;   // 0..4095
  biasP[c] = b_in[win_orig_row(c)];
}

// ---------------------------------------------------------------------------
// RMSNorm: one 256-thread block per row of 1024, bf16 output
// ---------------------------------------------------------------------------
__global__ __launch_bounds__(256)
void rmsnorm_kernel(const float* __restrict__ x, const float* __restrict__ w,
                    bf16* __restrict__ xn)
{
  const int row = blockIdx.x;
  const int tid = threadIdx.x;
  float4 v = ((const float4*)(x + (size_t)row * 1024))[tid];
  float ss = v.x * v.x + v.y * v.y + v.z * v.z + v.w * v.w;
  #pragma unroll
  for (int off = 1; off < 64; off <<= 1)
    ss += __shfl_xor(ss, off, 64);
  __shared__ float red[4];
  if ((tid & 63) == 0) red[tid >> 6] = ss;
  __syncthreads();
  float tot = red[0] + red[1] + red[2] + red[3];
  float rms = rsqrtf(tot * (1.0f / 1024.0f) + 1e-6f);
  float4 wv = ((const float4*)w)[tid];
  bf16x4 o;
  o[0] = (bf16)(v.x * rms * wv.x);
  o[1] = (bf16)(v.y * rms * wv.y);
  o[2] = (bf16)(v.z * rms * wv.z);
  o[3] = (bf16)(v.w * rms * wv.w);
  ((bf16x4*)(xn + (size_t)row * 1024))[tid] = o;
}

// ---------------------------------------------------------------------------
// 256x256 8-phase bf16 GEMM, C = A(MxK) * B(NxK)^T.
// 512 threads = 8 waves (2M x 4N); each wave: 128x64 out via 8x4 16x16x32 MFMA.
// BK=64, double-buffered LDS (128 KiB), counted vmcnt(4) at phases 4 & 8,
// setprio around MFMA clusters, XOR-swizzled read (pre-swizzled global src).
// MODE 1: paired {s=1-sigmoid, b=silu} bf16x2 epilogue -> sbw
// MODE 2: bias + residual -> fp32 out
// ---------------------------------------------------------------------------
DEV void stage_half(const bf16* __restrict__ P, int ldk, int grow0, int kt,
                    bf16* ldst, int tid)
{
  // one 128x64 half-tile = 2 global_load_lds per thread (16B each).
  // LDS dest linear; global source column-group XOR-preswizzled so the
  // swizzled ds_read below sees the right data (both-sides rule).
  #pragma unroll
  for (int s = 0; s < 2; ++s) {
    int cc  = (s << 9) + tid;          // chunk 0..1023 (8 bf16 each)
    int row = cc >> 3;                 // 0..127
    int kgg = (cc & 7) ^ (row & 7);
    async_load16(P + (size_t)(grow0 + row) * ldk + kt + kgg * 8, ldst + cc * 8);
  }
}

DEV bf16x8 ld_frag(const bf16* base, int r, int kg) {
  return *(const bf16x8*)(base + (((r << 3) + (kg ^ (r & 7))) << 3));
}

#define FENCE asm volatile("" ::: "memory")
#define BAR() do { FENCE; __builtin_amdgcn_s_barrier(); FENCE; } while (0)
#define LGKM0 asm volatile("s_waitcnt lgkmcnt(0)" ::: "memory")
#define VMC4  asm volatile("s_waitcnt vmcnt(4)" ::: "memory")
#define VMC0  asm volatile("s_waitcnt vmcnt(0)" ::: "memory")

#define LOADA(LAP, IH) \
  _Pragma("unroll") \
  for (int ii = 0; ii < 4; ++ii) { \
    _Pragma("unroll") \
    for (int ks = 0; ks < 2; ++ks) \
      af[ii][ks] = ld_frag(LAP, ((IH)*4 + ii)*16 + l15, ks*4 + quad); \
  }

#define LOADB(LBP, JH) \
  _Pragma("unroll") \
  for (int jj = 0; jj < 2; ++jj) { \
    _Pragma("unroll") \
    for (int ks = 0; ks < 2; ++ks) \
      bfr[(JH)*2 + jj][ks] = ld_frag(LBP, rBb + ((JH)*2 + jj)*16 + l15, ks*4 + quad); \
  }

#define MFMAQ(IH, JH) \
  _Pragma("unroll") \
  for (int ii = 0; ii < 4; ++ii) { \
    _Pragma("unroll") \
    for (int jj = 0; jj < 2; ++jj) { \
      _Pragma("unroll") \
      for (int ks = 0; ks < 2; ++ks) \
        acc[(IH)*4+ii][(JH)*2+jj] = __builtin_amdgcn_mfma_f32_16x16x32_bf16( \
            af[ii][ks], bfr[(JH)*2+jj][ks], acc[(IH)*4+ii][(JH)*2+jj], 0, 0, 0); \
    } \
  }

template <int MODE>
__global__ __launch_bounds__(512, 2)
void gemm256_kernel(const bf16* __restrict__ A, const bf16* __restrict__ B,
                    int N, int K, int numNt,
                    uint32_t* __restrict__ sbw, float* __restrict__ out,
                    const float* __restrict__ bias,
                    const float* __restrict__ resid)
{
  __shared__ __align__(16) bf16 lds[65536];   // 128 KiB: A[2buf][2half] | B[2buf][2half]

  // XCD-bijective swizzle (grid %8==0 for all our shapes) + GROUP_M supertile
  int nwg = gridDim.x;
  int bid = blockIdx.x;
  int cpx = nwg >> 3;
  int wg  = (bid & 7) * cpx + (bid >> 3);
  const int GROUP_M = 8;
  int per_group = GROUP_M * numNt;
  int group = wg / per_group;
  int rem   = wg - group * per_group;
  int mt = group * GROUP_M + (rem % GROUP_M);
  int nt = rem / GROUP_M;
  const int m0 = mt * 256, n0 = nt * 256;

  const int tid  = threadIdx.x;
  const int lane = tid & 63;
  const int wave = tid >> 6;
  const int wm   = wave >> 2;        // 0..1  (M half)
  const int wn   = wave & 3;         // 0..3  (N quarter)
  const int wh   = wn >> 1;          // B half this wave reads
  const int rBb  = (wn & 1) * 64;    // row base within B half
  const int l15  = lane & 15;
  const int quad = lane >> 4;

  // read-side base pointers (buffer x half)
  const bf16* lA0 = lds +         wm * 8192;
  const bf16* lA1 = lds + 16384 + wm * 8192;
  const bf16* lB0 = lds + 32768 + wh * 8192;
  const bf16* lB1 = lds + 49152 + wh * 8192;

  floatx4 acc[8][4];
  #pragma unroll
  for (int i = 0; i < 8; ++i)
    #pragma unroll
    for (int j = 0; j < 4; ++j)
      acc[i][j] = (floatx4){0.f, 0.f, 0.f, 0.f};

  bf16x8 af[4][2];    // A frags for one i-half (reloaded per K-phase)
  bf16x8 bfr[4][2];   // B frags, all 4 j, live across a K-tile

  // prologue: K-tile 0 fully + K-tile 1 B halves (12 loads/thread)
  stage_half(A, K, m0,       0, lds +     0, tid);
  stage_half(A, K, m0 + 128, 0, lds +  8192, tid);
  stage_half(B, K, n0,       0, lds + 32768, tid);
  stage_half(B, K, n0 + 128, 0, lds + 40960, tid);
  stage_half(B, K, n0,      64, lds + 49152, tid);
  stage_half(B, K, n0 + 128,64, lds + 57344, tid);
  VMC4;                 // first 8 (K-tile 0) complete, K1-B stays in flight
  BAR();

  const int U = K >> 7;               // iterations, 2 K-tiles each
  for (int u = 0; u < U; ++u) {
    const int k1 = (u << 7) + 64;     // K-tile 2u+1
    const int k2 = (u << 7) + 128;    // K-tile 2u+2
    const int k3 = (u << 7) + 192;    // K-tile 2u+3
    const bool more = (u + 1 < U);

    // ---- phase 1: buf0 reads A[0..3]+B[0..1]; stage A-odd h0 -> buf1
    LOADA(lA0, 0); LOADB(lB0, 0);
    stage_half(A, K, m0, k1, lds + 16384, tid);
    BAR(); LGKM0;
    __builtin_amdgcn_s_setprio(1); MFMAQ(0, 0); __builtin_amdgcn_s_setprio(0);
    BAR();
    // ---- phase 2: reads B[2..3]; stage A-odd h1
    LOADB(lB0, 1);
    stage_half(A, K, m0 + 128, k1, lds + 24576, tid);
    BAR(); LGKM0;
    __builtin_amdgcn_s_setprio(1); MFMAQ(0, 1); __builtin_amdgcn_s_setprio(0);
    BAR();
    // ---- phase 3: reads A[4..7]; stage B-next h0 -> buf0 (B-buf0 dead)
    LOADA(lA0, 1);
    if (more) stage_half(B, K, n0, k2, lds + 32768, tid);
    BAR(); LGKM0;
    __builtin_amdgcn_s_setprio(1); MFMAQ(1, 0); __builtin_amdgcn_s_setprio(0);
    BAR();
    // ---- phase 4: no reads; stage B-next h1; counted wait for buf1 readiness
    if (more) stage_half(B, K, n0 + 128, k2, lds + 40960, tid);
    BAR(); LGKM0;
    __builtin_amdgcn_s_setprio(1); MFMAQ(1, 1); __builtin_amdgcn_s_setprio(0);
    if (more) { VMC4; } else { VMC0; }   // completes A-odd + B-odd stages
    BAR();
    // ---- phase 5: buf1 reads A[0..3]+B[0..1]; stage A-next h0 (A-buf0 dead)
    LOADA(lA1, 0); LOADB(lB1, 0);
    if (more) stage_half(A, K, m0, k2, lds + 0, tid);
    BAR(); LGKM0;
    __builtin_amdgcn_s_setprio(1); MFMAQ(0, 0); __builtin_amdgcn_s_setprio(0);
    BAR();
    // ---- phase 6: reads B[2..3]; stage A-next h1
    LOADB(lB1, 1);
    if (more) stage_half(A, K, m0 + 128, k2, lds + 8192, tid);
    BAR(); LGKM0;
    __builtin_amdgcn_s_setprio(1); MFMAQ(0, 1); __builtin_amdgcn_s_setprio(0);
    BAR();
    // ---- phase 7: reads A[4..7]; stage B-odd' h0 -> buf1 (B-buf1 dead)
    LOADA(lA1, 1);
    if (more) stage_half(B, K, n0, k3, lds + 49152, tid);
    BAR(); LGKM0;
    __builtin_amdgcn_s_setprio(1); MFMAQ(1, 0); __builtin_amdgcn_s_setprio(0);
    BAR();
    // ---- phase 8: stage B-odd' h1; counted wait for next-iter buf0
    if (more) stage_half(B, K, n0 + 128, k3, lds + 57344, tid);
    BAR(); LGKM0;
    __builtin_amdgcn_s_setprio(1); MFMAQ(1, 1); __builtin_amdgcn_s_setprio(0);
    if (more) VMC4;                    // completes K-tile 2u+2 A+B stages
    BAR();
  }

  // epilogue. C/D layout: col = lane&15, row = quad*4 + reg
  if (MODE == 1) {
    #pragma unroll
    for (int i = 0; i < 8; ++i) {
      #pragma unroll
      for (int pair = 0; pair < 2; ++pair) {
        int colb = n0 + wn * 64 + pair * 32;
        float bs = bias[colb + l15];
        float bb = bias[colb + 16 + l15];
        int ch = (colb >> 5) * 16 + l15;           // logical channel
        #pragma unroll
        for (int r = 0; r < 4; ++r) {
          int row = m0 + wm * 128 + i * 16 + quad * 4 + r;
          float vs = acc[i][pair * 2][r] + bs;
          float vb = acc[i][pair * 2 + 1][r] + bb;
          // s = 1 - sigmoid(vs) = 1/(1+exp(vs))
          float s  = 1.0f / (1.0f + __expf(vs));
          // b = silu(vb)
          float sv = 1.0f / (1.0f + __expf(vb));
          float bv = vb - vb * sv;
          union { bf16 h[2]; uint32_t u; } pk;
          pk.h[0] = (bf16)s;
          pk.h[1] = (bf16)bv;
          sbw[(size_t)row * 2048 + ch] = pk.u;
        }
      }
    }
  } else {
    #pragma unroll
    for (int i = 0; i < 8; ++i) {
      #pragma unroll
      for (int j = 0; j < 4; ++j) {
        int col = n0 + wn * 64 + j * 16 + l15;
        float bc = bias[col];
        #pragma unroll
        for (int r = 0; r < 4; ++r) {
          int row = m0 + wm * 128 + i * 16 + quad * 4 + r;
          float v = acc[i][j][r] + bc + resid[(size_t)row * N + col];
          out[(size_t)row * N + col] = v;
        }
      }
    }
  }
}

// ---------------------------------------------------------------------------
// Chunked scan over BSl sequences of N=8192: 32 chunks x 256 steps.
// sb: interleaved {s=1-a, b} bf16 pairs, one uint32 per element.
// ---------------------------------------------------------------------------
__global__ __launch_bounds__(256)
void scan_phase1(const uint32_t* __restrict__ sb,
                 float* __restrict__ Ac, float* __restrict__ Bc)
{
  int g = blockIdx.x * 256 + threadIdx.x;    // [seq][chunk][e]
  int e     = g & 2047;
  int chunk = (g >> 11) & 31;
  int seq   = g >> 16;
  size_t base = ((size_t)(seq * 8192 + chunk * 256)) * 2048 + e;
  float A = 1.0f, Bv = 0.0f;
  #pragma unroll 8
  for (int n = 0; n < 256; ++n) {
    uint32_t pv = sb[base + (size_t)n * 2048];
    float a = 1.0f - bf16lo_to_f(pv);
    float b = bf16hi_to_f(pv);
    A *= a;
    Bv = a * Bv + b;
  }
  Ac[g] = A;
  Bc[g] = Bv;
}

__global__ __launch_bounds__(256)
void scan_phase2(const float* __restrict__ Ac, const float* __restrict__ Bc,
                 const float* __restrict__ h_prev,
                 float* __restrict__ carry, float* __restrict__ h_last)
{
  int g = blockIdx.x * 256 + threadIdx.x;    // seq*2048 + e
  int e = g & 2047;
  int seq = g >> 11;
  float h = h_prev[g];
  #pragma unroll
  for (int c = 0; c < 32; ++c) {
    size_t idx = ((size_t)(seq * 32 + c)) * 2048 + e;
    carry[idx] = h;
    h = Ac[idx] * h + Bc[idx];
  }
  h_last[g] = h;
}

__global__ __launch_bounds__(256)
void scan_phase3(const uint32_t* __restrict__ sb,
                 const float* __restrict__ carry, bf16* __restrict__ h_out)
{
  int g = blockIdx.x * 256 + threadIdx.x;
  int e     = g & 2047;
  int chunk = (g >> 11) & 31;
  int seq   = g >> 16;
  float h = carry[((size_t)(seq * 32 + chunk)) * 2048 + e];
  size_t base = ((size_t)(seq * 8192 + chunk * 256)) * 2048 + e;
  #pragma unroll 8
  for (int n = 0; n < 256; ++n) {
    uint32_t pv = sb[base + (size_t)n * 2048];
    float a = 1.0f - bf16lo_to_f(pv);
    float b = bf16hi_to_f(pv);
    h = a * h + b;
    h_out[base + (size_t)n * 2048] = (bf16)h;
  }
}

// ---------------------------------------------------------------------------
extern "C" void kernel_launch(void* const* d_in, const int* in_sizes, int n_in,
                              void* d_out, int out_size, void* d_ws, size_t ws_size,
                              hipStream_t stream)
{
  const float* x      = (const float*)d_in[0];   // (4, 8192, 1024)
  const float* h_prev = (const float*)d_in[1];   // (4, 2048)
  const float* norm_w = (const float*)d_in[2];   // (1024,)
  const float* W_in   = (const float*)d_in[3];   // (4096, 1024)
  const float* b_in   = (const float*)d_in[4];   // (4096,)
  const float* W_out  = (const float*)d_in[5];   // (1024, 2048)
  const float* b_out  = (const float*)d_in[6];   // (1024,)

  float* out    = (float*)d_out;                 // 33554432 fp32
  float* h_last = out + (size_t)33554432;        // + 8192 fp32

  // ws layout; full (BSl=4) needs ~463 MB, fallback BSl=1 runs 4 passes.
  int BSl = 4, passes = 1;
  {
    size_t need4 = 8388608 + 4194304 + 16384
                 + 3 * ((size_t)4 * 32 * 2048 * 4)
                 + (size_t)4 * 8192 * 2048 * 4
                 + (size_t)4 * 8192 * 1024 * 2
                 + (size_t)4 * 8192 * 2048 * 2;
    if (ws_size < need4) { BSl = 1; passes = 4; }
  }
  const size_t Mrows = (size_t)BSl * 8192;
  char* ws = (char*)d_ws;
  bf16*  Win_b  = (bf16*)(ws);                       // 8 MB (permuted rows)
  bf16*  Wout_b = (bf16*)(ws + 8388608);             // 4 MB
  float* biasP  = (float*)(ws + 12582912);           // 16 KB (permuted b_in)
  size_t acN    = (size_t)BSl * 32 * 2048;           // chunk aggregates
  char*  pa     = ws + 12599296;
  float* Ac     = (float*)(pa);
  float* Bc     = (float*)(pa + acN * 4);
  float* carry  = (float*)(pa + acN * 8);
  char*  p0     = pa + acN * 12;
  uint32_t* sbw = (uint32_t*)(p0);                   // Mrows*2048*4 B
  bf16*  xn     = (bf16*)(p0 + Mrows * 2048 * 4);    // Mrows*1024*2 B
  bf16*  h_arr  = (bf16*)(p0 + Mrows * 2048 * 4 + Mrows * 1024 * 2);

  f2bf_win_perm<<<4096, 256, 0, stream>>>(W_in, Win_b);
  f2bf_kernel<<<2048, 256, 0, stream>>>(W_out, Wout_b, 2097152 / 4);
  bias_perm_kernel<<<16, 256, 0, stream>>>(b_in, biasP);

  for (int p = 0; p < passes; ++p) {
    const float* xp = x + (size_t)p * Mrows * 1024;

    rmsnorm_kernel<<<(int)Mrows, 256, 0, stream>>>(xp, norm_w, xn);

    // GEMM1: (Mrows x 1024) x (4096 x 1024)^T, fused paired sigmoid/silu
    int numMt = (int)(Mrows / 256);
    gemm256_kernel<1><<<numMt * 16, 512, 0, stream>>>(
        xn, Win_b, 4096, 1024, 16, sbw, nullptr, biasP, nullptr);

    scan_phase1<<<BSl * 256, 256, 0, stream>>>(sbw, Ac, Bc);
    scan_phase2<<<BSl * 8, 256, 0, stream>>>(Ac, Bc, h_prev + (size_t)p * BSl * 2048,
                                             carry, h_last + (size_t)p * BSl * 2048);
    scan_phase3<<<BSl * 256, 256, 0, stream>>>(sbw, carry, h_arr);

    // GEMM2: (Mrows x 2048) x (1024 x 2048)^T, fused bias + residual
    gemm256_kernel<2><<<numMt * 4, 512, 0, stream>>>(
        h_arr, Wout_b, 1024, 2048, 4, nullptr, out + (size_t)p * Mrows * 1024,
        b_out, xp);
  }
}

// Round 3
// 798.580 us; speedup vs baseline: 1.2124x; 1.0018x over previous
//
#include <hip/hip_runtime.h>
#include <stdint.h>
#include <stddef.h>

typedef __bf16 bf16;
typedef __attribute__((ext_vector_type(8))) __bf16 bf16x8;
typedef __attribute__((ext_vector_type(4))) __bf16 bf16x4;
typedef __attribute__((ext_vector_type(4))) float floatx4;

#define DEV static __device__ __forceinline__

// async global->LDS, 16B per lane. LDS dest is wave-uniform base + lane*16.
DEV void async_load16(const void* g, void* l) {
  __builtin_amdgcn_global_load_lds(
      (__attribute__((address_space(1))) void*)(g),
      (__attribute__((address_space(3))) void*)(l),
      16, 0, 0);
}

DEV float bf16lo_to_f(uint32_t pv) {
  uint32_t b = pv << 16; float f; __builtin_memcpy(&f, &b, 4); return f;
}
DEV float bf16hi_to_f(uint32_t pv) {
  uint32_t b = pv & 0xffff0000u; float f; __builtin_memcpy(&f, &b, 4); return f;
}

// W_in row permutation: new row c holds logical channel p = (c>>5)*16 + (c&15),
// s-half if (c>>4)&1 == 0 else b-half (orig row p + 2048).
DEV int win_orig_row(int c) {
  int jt16 = c >> 4;
  int is_b = jt16 & 1;
  int p    = (jt16 >> 1) * 16 + (c & 15);
  return p + is_b * 2048;
}

// ---------------------------------------------------------------------------
// fp32 -> bf16 convert (generic, for W_out)
// ---------------------------------------------------------------------------
__global__ __launch_bounds__(256)
void f2bf_kernel(const float* __restrict__ in, bf16* __restrict__ out, int n4)
{
  int i = blockIdx.x * 256 + threadIdx.x;
  if (i < n4) {
    float4 v = ((const float4*)in)[i];
    bf16x4 o = { (bf16)v.x, (bf16)v.y, (bf16)v.z, (bf16)v.w };
    ((bf16x4*)out)[i] = o;
  }
}

// fp32 -> bf16 convert of W_in with row permutation (one block per new row)
__global__ __launch_bounds__(256)
void f2bf_win_perm(const float* __restrict__ in, bf16* __restrict__ out)
{
  int c = blockIdx.x;                    // new row 0..4095
  int orig = win_orig_row(c);
  float4 v = ((const float4*)(in + (size_t)orig * 1024))[threadIdx.x];
  bf16x4 o = { (bf16)v.x, (bf16)v.y, (bf16)v.z, (bf16)v.w };
  ((bf16x4*)(out + (size_t)c * 1024))[threadIdx.x] = o;
}

__global__ __launch_bounds__(256)
void bias_perm_kernel(const float* __restrict__ b_in, float* __restrict__ biasP)
{
  int c = blockIdx.x * 256 + threadIdx.x;   // 0..4095
  biasP[c] = b_in[win_orig_row(c)];
}

// ---------------------------------------------------------------------------
// RMSNorm: one 256-thread block per row of 1024, bf16 output
// ---------------------------------------------------------------------------
__global__ __launch_bounds__(256)
void rmsnorm_kernel(const float* __restrict__ x, const float* __restrict__ w,
                    bf16* __restrict__ xn)
{
  const int row = blockIdx.x;
  const int tid = threadIdx.x;
  float4 v = ((const float4*)(x + (size_t)row * 1024))[tid];
  float ss = v.x * v.x + v.y * v.y + v.z * v.z + v.w * v.w;
  #pragma unroll
  for (int off = 1; off < 64; off <<= 1)
    ss += __shfl_xor(ss, off, 64);
  __shared__ float red[4];
  if ((tid & 63) == 0) red[tid >> 6] = ss;
  __syncthreads();
  float tot = red[0] + red[1] + red[2] + red[3];
  float rms = rsqrtf(tot * (1.0f / 1024.0f) + 1e-6f);
  float4 wv = ((const float4*)w)[tid];
  bf16x4 o;
  o[0] = (bf16)(v.x * rms * wv.x);
  o[1] = (bf16)(v.y * rms * wv.y);
  o[2] = (bf16)(v.z * rms * wv.z);
  o[3] = (bf16)(v.w * rms * wv.w);
  ((bf16x4*)(xn + (size_t)row * 1024))[tid] = o;
}

// ---------------------------------------------------------------------------
// 256x256 8-phase bf16 GEMM, C = A(MxK) * B(NxK)^T.
// 512 threads = 8 waves (2M x 4N); each wave: 128x64 out via 8x4 16x16x32 MFMA.
// BK=64, double-buffered LDS (128 KiB), counted vmcnt(4) at phases 4 & 8,
// setprio around MFMA clusters, XOR-swizzled read (pre-swizzled global src).
// All ds_read addresses hoisted into 4 base pointers + immediate offsets;
// no explicit lgkmcnt(0) (compiler emits fine-grained partial waits);
// last iteration peeled — NOTE: the peel MUST still stage A-odd at kF=K-64
// (phases 1/2 stage in-iteration even on the last iteration).
// MODE 1: paired {s=1-sigmoid, b=silu} bf16x2 epilogue -> sbw
// MODE 2: bias + residual -> fp32 out
// ---------------------------------------------------------------------------
#define FENCE asm volatile("" ::: "memory")
#define BAR() do { FENCE; __builtin_amdgcn_s_barrier(); FENCE; } while (0)
#define VMC4  asm volatile("s_waitcnt vmcnt(4)" ::: "memory")
#define VMC0  asm volatile("s_waitcnt vmcnt(0)" ::: "memory")
#define PRIO1 __builtin_amdgcn_s_setprio(1)
#define PRIO0 __builtin_amdgcn_s_setprio(0)

// LDS element offsets of the 8 staging regions
#define RA00 0
#define RA01 8192
#define RA10 16384
#define RA11 24576
#define RB00 32768
#define RB01 40960
#define RB10 49152
#define RB11 57344

// load A fragments for i-half IH from buffer BUF (offsets compile-time)
#define LOADA(BUF, IH) \
  _Pragma("unroll") \
  for (int ii = 0; ii < 4; ++ii) { \
    af[ii][0] = *(const bf16x8*)(pA0 + ((BUF)*16384 + (IH)*4096 + ii*1024)); \
    af[ii][1] = *(const bf16x8*)(pA1 + ((BUF)*16384 + (IH)*4096 + ii*1024)); \
  }

// load B fragments for j-half JH from buffer BUF
#define LOADB(BUF, JH) \
  _Pragma("unroll") \
  for (int jj = 0; jj < 2; ++jj) { \
    bfr[(JH)*2+jj][0] = *(const bf16x8*)(pB0 + ((BUF)*16384 + ((JH)*2+jj)*1024)); \
    bfr[(JH)*2+jj][1] = *(const bf16x8*)(pB1 + ((BUF)*16384 + ((JH)*2+jj)*1024)); \
  }

#define MFMAQ(IH, JH) \
  _Pragma("unroll") \
  for (int ii = 0; ii < 4; ++ii) { \
    _Pragma("unroll") \
    for (int jj = 0; jj < 2; ++jj) { \
      _Pragma("unroll") \
      for (int ks = 0; ks < 2; ++ks) \
        acc[(IH)*4+ii][(JH)*2+jj] = __builtin_amdgcn_mfma_f32_16x16x32_bf16( \
            af[ii][ks], bfr[(JH)*2+jj][ks], acc[(IH)*4+ii][(JH)*2+jj], 0, 0, 0); \
    } \
  }

// stage one 128x64 half-tile: 2 x global_load_lds(16B) per thread
#define STAGE(G0, G1, REGION, KT) do { \
  async_load16((G0) + (KT), sd0 + (REGION)); \
  async_load16((G1) + (KT), sd1 + (REGION)); } while (0)

template <int MODE>
__global__ __launch_bounds__(512, 2)
void gemm256_kernel(const bf16* __restrict__ A, const bf16* __restrict__ B,
                    int N, int K, int numNt,
                    uint32_t* __restrict__ sbw, float* __restrict__ out,
                    const float* __restrict__ bias,
                    const float* __restrict__ resid)
{
  __shared__ __align__(16) bf16 lds[65536];   // 128 KiB: A[2buf][2half] | B[2buf][2half]

  // XCD-bijective swizzle (grid %8==0 for all our shapes) + GROUP_M supertile
  int nwg = gridDim.x;
  int bid = blockIdx.x;
  int cpx = nwg >> 3;
  int wg  = (bid & 7) * cpx + (bid >> 3);
  const int GROUP_M = 8;
  int per_group = GROUP_M * numNt;
  int group = wg / per_group;
  int rem   = wg - group * per_group;
  int mt = group * GROUP_M + (rem % GROUP_M);
  int nt = rem / GROUP_M;
  const int m0 = mt * 256, n0 = nt * 256;

  const int tid  = threadIdx.x;
  const int lane = tid & 63;
  const int wave = tid >> 6;
  const int wm   = wave >> 2;        // 0..1  (M half)
  const int wn   = wave & 3;         // 0..3  (N quarter)
  const int wh   = wn >> 1;          // B half this wave reads
  const int rBb  = (wn & 1) * 64;    // row base within B half
  const int l15  = lane & 15;
  const int quad = lane >> 4;
  const int l7   = l15 & 7;

  // ---- hoisted LDS read base pointers (elements); everything else is an
  // ---- immediate offset folded into ds_read_b128 offset:
  const bf16* pA0 = lds + wm * 8192 + l15 * 64 + ((quad ^ l7) << 3);
  const bf16* pA1 = lds + wm * 8192 + l15 * 64 + (((4 + quad) ^ l7) << 3);
  const bf16* pB0 = lds + 32768 + wh * 8192 + (rBb + l15) * 64 + ((quad ^ l7) << 3);
  const bf16* pB1 = lds + 32768 + wh * 8192 + (rBb + l15) * 64 + (((4 + quad) ^ l7) << 3);

  // ---- hoisted global staging pointers (pre-swizzled source columns)
  const int cc1 = 512 + tid;
  const int r0 = tid >> 3, x0 = ((tid & 7) ^ (r0 & 7)) << 3;
  const int r1 = cc1 >> 3, x1 = ((cc1 & 7) ^ (r1 & 7)) << 3;
  const bf16* gA00 = A + (size_t)(m0 + r0) * K + x0;   // rows 0..63
  const bf16* gA01 = A + (size_t)(m0 + r1) * K + x1;   // rows 64..127
  const bf16* gA10 = gA00 + (size_t)128 * K;           // rows 128..191
  const bf16* gA11 = gA01 + (size_t)128 * K;           // rows 192..255
  const bf16* gB00 = B + (size_t)(n0 + r0) * K + x0;
  const bf16* gB01 = B + (size_t)(n0 + r1) * K + x1;
  const bf16* gB10 = gB00 + (size_t)128 * K;
  const bf16* gB11 = gB01 + (size_t)128 * K;
  bf16* sd0 = lds + tid * 8;           // + REGION
  bf16* sd1 = lds + 4096 + tid * 8;

  floatx4 acc[8][4];
  #pragma unroll
  for (int i = 0; i < 8; ++i)
    #pragma unroll
    for (int j = 0; j < 4; ++j)
      acc[i][j] = (floatx4){0.f, 0.f, 0.f, 0.f};

  bf16x8 af[4][2];    // A frags for one i-half
  bf16x8 bfr[4][2];   // B frags, all 4 j, live across a K-tile

  // prologue: K-tile 0 fully + K-tile 1 B halves (12 loads/thread)
  STAGE(gA00, gA01, RA00, 0);
  STAGE(gA10, gA11, RA01, 0);
  STAGE(gB00, gB01, RB00, 0);
  STAGE(gB10, gB11, RB01, 0);
  STAGE(gB00, gB01, RB10, 64);
  STAGE(gB10, gB11, RB11, 64);
  VMC4;                 // first 8 (K-tile 0) complete, K1-B stays in flight
  BAR();

  const int U = K >> 7;               // iterations, 2 K-tiles each
  for (int u = 0; u < U - 1; ++u) {
    const int k1 = (u << 7) + 64;     // K-tile 2u+1
    const int k2 = (u << 7) + 128;    // K-tile 2u+2
    const int k3 = (u << 7) + 192;    // K-tile 2u+3

    // ---- phase 1: buf0 reads A[0..3]+B[0..1]; stage A-odd h0 -> buf1
    LOADA(0, 0); LOADB(0, 0);
    STAGE(gA00, gA01, RA10, k1);
    BAR();
    PRIO1; MFMAQ(0, 0); PRIO0;
    BAR();
    // ---- phase 2: reads B[2..3]; stage A-odd h1
    LOADB(0, 1);
    STAGE(gA10, gA11, RA11, k1);
    BAR();
    PRIO1; MFMAQ(0, 1); PRIO0;
    BAR();
    // ---- phase 3: reads A[4..7]; stage B-next h0 -> buf0 (B-buf0 dead)
    LOADA(0, 1);
    STAGE(gB00, gB01, RB00, k2);
    BAR();
    PRIO1; MFMAQ(1, 0); PRIO0;
    BAR();
    // ---- phase 4: stage B-next h1; counted wait for buf1 readiness
    STAGE(gB10, gB11, RB01, k2);
    BAR();
    PRIO1; MFMAQ(1, 1); PRIO0;
    VMC4;                              // completes A-odd + B-odd stages
    BAR();
    // ---- phase 5: buf1 reads A[0..3]+B[0..1]; stage A-next h0 (A-buf0 dead)
    LOADA(1, 0); LOADB(1, 0);
    STAGE(gA00, gA01, RA00, k2);
    BAR();
    PRIO1; MFMAQ(0, 0); PRIO0;
    BAR();
    // ---- phase 6: reads B[2..3]; stage A-next h1
    LOADB(1, 1);
    STAGE(gA10, gA11, RA01, k2);
    BAR();
    PRIO1; MFMAQ(0, 1); PRIO0;
    BAR();
    // ---- phase 7: reads A[4..7]; stage B-odd' h0 -> buf1 (B-buf1 dead)
    LOADA(1, 1);
    STAGE(gB00, gB01, RB10, k3);
    BAR();
    PRIO1; MFMAQ(1, 0); PRIO0;
    BAR();
    // ---- phase 8: stage B-odd' h1; counted wait for next-iter buf0
    STAGE(gB10, gB11, RB11, k3);
    BAR();
    PRIO1; MFMAQ(1, 1); PRIO0;
    VMC4;                              // completes K-tile 2u+2 A+B stages
    BAR();
  }

  // ---- peeled final iteration: A-odd staging at kF STILL required;
  // ---- only k2/k3 (beyond-K) stages are dropped. VMC0 drains before buf1.
  {
    const int kF = ((U - 1) << 7) + 64;     // final K-tile
    LOADA(0, 0); LOADB(0, 0);
    STAGE(gA00, gA01, RA10, kF);
    BAR(); PRIO1; MFMAQ(0, 0); PRIO0; BAR();
    LOADB(0, 1);
    STAGE(gA10, gA11, RA11, kF);
    BAR(); PRIO1; MFMAQ(0, 1); PRIO0; BAR();
    LOADA(0, 1);
    BAR(); PRIO1; MFMAQ(1, 0); PRIO0; BAR();
    BAR(); PRIO1; MFMAQ(1, 1); PRIO0;
    VMC0;                              // drain A-odd(kF) + B-odd'(kF)
    BAR();
    LOADA(1, 0); LOADB(1, 0);
    BAR(); PRIO1; MFMAQ(0, 0); PRIO0; BAR();
    LOADB(1, 1);
    BAR(); PRIO1; MFMAQ(0, 1); PRIO0; BAR();
    LOADA(1, 1);
    BAR(); PRIO1; MFMAQ(1, 0); PRIO0; BAR();
    PRIO1; MFMAQ(1, 1); PRIO0;
  }

  // epilogue. C/D layout: col = lane&15, row = quad*4 + reg
  if (MODE == 1) {
    #pragma unroll
    for (int i = 0; i < 8; ++i) {
      #pragma unroll
      for (int pair = 0; pair < 2; ++pair) {
        int colb = n0 + wn * 64 + pair * 32;
        float bs = bias[colb + l15];
        float bb = bias[colb + 16 + l15];
        int ch = (colb >> 5) * 16 + l15;           // logical channel
        #pragma unroll
        for (int r = 0; r < 4; ++r) {
          int row = m0 + wm * 128 + i * 16 + quad * 4 + r;
          float vs = acc[i][pair * 2][r] + bs;
          float vb = acc[i][pair * 2 + 1][r] + bb;
          // s = 1 - sigmoid(vs) = 1/(1+exp(vs))
          float s  = 1.0f / (1.0f + __expf(vs));
          // b = silu(vb)
          float sv = 1.0f / (1.0f + __expf(vb));
          float bv = vb - vb * sv;
          union { bf16 h[2]; uint32_t u; } pk;
          pk.h[0] = (bf16)s;
          pk.h[1] = (bf16)bv;
          sbw[(size_t)row * 2048 + ch] = pk.u;
        }
      }
    }
  } else {
    #pragma unroll
    for (int i = 0; i < 8; ++i) {
      #pragma unroll
      for (int j = 0; j < 4; ++j) {
        int col = n0 + wn * 64 + j * 16 + l15;
        float bc = bias[col];
        #pragma unroll
        for (int r = 0; r < 4; ++r) {
          int row = m0 + wm * 128 + i * 16 + quad * 4 + r;
          float v = acc[i][j][r] + bc + resid[(size_t)row * N + col];
          out[(size_t)row * N + col] = v;
        }
      }
    }
  }
}

// ---------------------------------------------------------------------------
// Chunked scan over BSl sequences of N=8192: 32 chunks x 256 steps.
// sb: interleaved {s=1-a, b} bf16 pairs, one uint32 per element.
// ---------------------------------------------------------------------------
__global__ __launch_bounds__(256)
void scan_phase1(const uint32_t* __restrict__ sb,
                 float* __restrict__ Ac, float* __restrict__ Bc)
{
  int g = blockIdx.x * 256 + threadIdx.x;    // [seq][chunk][e]
  int e     = g & 2047;
  int chunk = (g >> 11) & 31;
  int seq   = g >> 16;
  size_t base = ((size_t)(seq * 8192 + chunk * 256)) * 2048 + e;
  float A = 1.0f, Bv = 0.0f;
  #pragma unroll 8
  for (int n = 0; n < 256; ++n) {
    uint32_t pv = sb[base + (size_t)n * 2048];
    float a = 1.0f - bf16lo_to_f(pv);
    float b = bf16hi_to_f(pv);
    A *= a;
    Bv = a * Bv + b;
  }
  Ac[g] = A;
  Bc[g] = Bv;
}

__global__ __launch_bounds__(256)
void scan_phase2(const float* __restrict__ Ac, const float* __restrict__ Bc,
                 const float* __restrict__ h_prev,
                 float* __restrict__ carry, float* __restrict__ h_last)
{
  int g = blockIdx.x * 256 + threadIdx.x;    // seq*2048 + e
  int e = g & 2047;
  int seq = g >> 11;
  float h = h_prev[g];
  #pragma unroll
  for (int c = 0; c < 32; ++c) {
    size_t idx = ((size_t)(seq * 32 + c)) * 2048 + e;
    carry[idx] = h;
    h = Ac[idx] * h + Bc[idx];
  }
  h_last[g] = h;
}

__global__ __launch_bounds__(256)
void scan_phase3(const uint32_t* __restrict__ sb,
                 const float* __restrict__ carry, bf16* __restrict__ h_out)
{
  int g = blockIdx.x * 256 + threadIdx.x;
  int e     = g & 2047;
  int chunk = (g >> 11) & 31;
  int seq   = g >> 16;
  float h = carry[((size_t)(seq * 32 + chunk)) * 2048 + e];
  size_t base = ((size_t)(seq * 8192 + chunk * 256)) * 2048 + e;
  #pragma unroll 8
  for (int n = 0; n < 256; ++n) {
    uint32_t pv = sb[base + (size_t)n * 2048];
    float a = 1.0f - bf16lo_to_f(pv);
    float b = bf16hi_to_f(pv);
    h = a * h + b;
    h_out[base + (size_t)n * 2048] = (bf16)h;
  }
}

// ---------------------------------------------------------------------------
extern "C" void kernel_launch(void* const* d_in, const int* in_sizes, int n_in,
                              void* d_out, int out_size, void* d_ws, size_t ws_size,
                              hipStream_t stream)
{
  const float* x      = (const float*)d_in[0];   // (4, 8192, 1024)
  const float* h_prev = (const float*)d_in[1];   // (4, 2048)
  const float* norm_w = (const float*)d_in[2];   // (1024,)
  const float* W_in   = (const float*)d_in[3];   // (4096, 1024)
  const float* b_in   = (const float*)d_in[4];   // (4096,)
  const float* W_out  = (const float*)d_in[5];   // (1024, 2048)
  const float* b_out  = (const float*)d_in[6];   // (1024,)

  float* out    = (float*)d_out;                 // 33554432 fp32
  float* h_last = out + (size_t)33554432;        // + 8192 fp32

  // ws layout; full (BSl=4) needs ~463 MB, fallback BSl=1 runs 4 passes.
  int BSl = 4, passes = 1;
  {
    size_t need4 = 8388608 + 4194304 + 16384
                 + 3 * ((size_t)4 * 32 * 2048 * 4)
                 + (size_t)4 * 8192 * 2048 * 4
                 + (size_t)4 * 8192 * 1024 * 2
                 + (size_t)4 * 8192 * 2048 * 2;
    if (ws_size < need4) { BSl = 1; passes = 4; }
  }
  const size_t Mrows = (size_t)BSl * 8192;
  char* ws = (char*)d_ws;
  bf16*  Win_b  = (bf16*)(ws);                       // 8 MB (permuted rows)
  bf16*  Wout_b = (bf16*)(ws + 8388608);             // 4 MB
  float* biasP  = (float*)(ws + 12582912);           // 16 KB (permuted b_in)
  size_t acN    = (size_t)BSl * 32 * 2048;           // chunk aggregates
  char*  pa     = ws + 12599296;
  float* Ac     = (float*)(pa);
  float* Bc     = (float*)(pa + acN * 4);
  float* carry  = (float*)(pa + acN * 8);
  char*  p0     = pa + acN * 12;
  uint32_t* sbw = (uint32_t*)(p0);                   // Mrows*2048*4 B
  bf16*  xn     = (bf16*)(p0 + Mrows * 2048 * 4);    // Mrows*1024*2 B
  bf16*  h_arr  = (bf16*)(p0 + Mrows * 2048 * 4 + Mrows * 1024 * 2);

  f2bf_win_perm<<<4096, 256, 0, stream>>>(W_in, Win_b);
  f2bf_kernel<<<2048, 256, 0, stream>>>(W_out, Wout_b, 2097152 / 4);
  bias_perm_kernel<<<16, 256, 0, stream>>>(b_in, biasP);

  for (int p = 0; p < passes; ++p) {
    const float* xp = x + (size_t)p * Mrows * 1024;

    rmsnorm_kernel<<<(int)Mrows, 256, 0, stream>>>(xp, norm_w, xn);

    // GEMM1: (Mrows x 1024) x (4096 x 1024)^T, fused paired sigmoid/silu
    int numMt = (int)(Mrows / 256);
    gemm256_kernel<1><<<numMt * 16, 512, 0, stream>>>(
        xn, Win_b, 4096, 1024, 16, sbw, nullptr, biasP, nullptr);

    scan_phase1<<<BSl * 256, 256, 0, stream>>>(sbw, Ac, Bc);
    scan_phase2<<<BSl * 8, 256, 0, stream>>>(Ac, Bc, h_prev + (size_t)p * BSl * 2048,
                                             carry, h_last + (size_t)p * BSl * 2048);
    scan_phase3<<<BSl * 256, 256, 0, stream>>>(sbw, carry, h_arr);

    // GEMM2: (Mrows x 2048) x (1024 x 2048)^T, fused bias + residual
    gemm256_kernel<2><<<numMt * 4, 512, 0, stream>>>(
        h_arr, Wout_b, 1024, 2048, 4, nullptr, out + (size_t)p * Mrows * 1024,
        b_out, xp);
  }
}